// Round 6
// baseline (123.305 us; speedup 1.0000x reference)
//
#include <hip/hip_runtime.h>
#include <stdint.h>

// BitNetLinear eval forward on MI355X (gfx950).
// M = B*S = 32768, K = 1024 (in_features), N = 1024 (out_features).
//
// R5: kquant_x ELIMINATED. Fused GEMM: each block owns 64 M-rows x full N;
// reads its x rows fp32 once, quantizes in-register (x * (1/i_scale), ~1ulp
// vs IEEE div -> off-by-one q in ~1e-6 of elems, each worth 0.0026 in out;
// threshold 0.236), stores int8 A in swizzled LDS, then a BARRIER-FREE
// K-loop: af from LDS, bf from L2-resident qw with static double-buffered
// prefetch. HBM total drops ~490 -> ~390 MB.
// Pipeline: kprep (max|x| + sum|W|) -> kquant_w (w_scale + ternary qw) ->
// kfused (i_scale reduce + quant-A + MFMA GEMM + dequant epilogue).

#define MK_M 32768
#define MK_K 1024
#define MK_N 1024

typedef __attribute__((ext_vector_type(4))) int int32x4;

// ---- workspace layout ----
// [0]    float w_scale      [4] float i_scale (unused now, kept)
// [64]   float maxp[2048]   (per-block |x| maxima, rewritten every call)
// [8448] double partials[64](|W| partial sums, rewritten every call)
// [16384] qw (1 MB)
#define WS_MAXP_OFF 64
#define WS_PART_OFF 8448
#define WS_QW_OFF 16384
#define WS_NEEDED (WS_QW_OFF + (1 << 20))

// fused: blocks [0,2048) -> per-block max|x|; blocks [2048,2112) -> partial sum|W|
__global__ void kprep(const float4* __restrict__ x4, const float4* __restrict__ w4,
                      float* __restrict__ maxp, double* __restrict__ partials, long n4x) {
    const int bid = blockIdx.x;
    if (bid < 2048) {
        float m = 0.f;
        const long stride = 2048L * 256;
        for (long i = (long)bid * 256 + threadIdx.x; i < n4x; i += stride) {
            float4 v = x4[i];
            m = fmaxf(m, fmaxf(fmaxf(fabsf(v.x), fabsf(v.y)), fmaxf(fabsf(v.z), fabsf(v.w))));
        }
        #pragma unroll
        for (int off = 1; off < 64; off <<= 1) m = fmaxf(m, __shfl_xor(m, off));
        __shared__ float sm[4];
        int lane = threadIdx.x & 63, wid = threadIdx.x >> 6;
        if (lane == 0) sm[wid] = m;
        __syncthreads();
        if (threadIdx.x == 0) maxp[bid] = fmaxf(fmaxf(sm[0], sm[1]), fmaxf(sm[2], sm[3]));
    } else {
        double s = 0.0;
        for (int i = (bid - 2048) * 256 + threadIdx.x; i < (1 << 18); i += 64 * 256) {
            float4 v = w4[i];
            s += (double)fabsf(v.x);
            s += (double)fabsf(v.y);
            s += (double)fabsf(v.z);
            s += (double)fabsf(v.w);
        }
        __shared__ double sd[256];
        sd[threadIdx.x] = s;
        __syncthreads();
        for (int h = 128; h > 0; h >>= 1) {
            if ((int)threadIdx.x < h) sd[threadIdx.x] += sd[threadIdx.x + h];
            __syncthreads();
        }
        if (threadIdx.x == 0) partials[bid - 2048] = sd[0];
    }
}

// every block redundantly reduces partials[64] in the SAME fixed order
// (butterfly over wave 0) -> identical deterministic w_scale everywhere.
__global__ void kquant_w(const float4* __restrict__ w4, unsigned* __restrict__ qw,
                         const double* __restrict__ partials, float* __restrict__ wscp) {
    __shared__ double sws;
    if (threadIdx.x < 64) {
        double s = partials[threadIdx.x];
        #pragma unroll
        for (int off = 1; off < 64; off <<= 1) s += __shfl_xor(s, off);
        if (threadIdx.x == 0) sws = s;
    }
    __syncthreads();
    float wsc = (float)(sws / 1048576.0);   // mean|W| over 2^20 elements
    if (blockIdx.x == 0 && threadIdx.x == 0) *wscp = wsc;
    float thr = 0.5f * wsc;
    int stride = gridDim.x * blockDim.x;
    for (int i = blockIdx.x * blockDim.x + threadIdx.x; i < (1 << 18); i += stride) {
        float4 v = w4[i];
        int q0 = (fabsf(v.x) > thr) ? (v.x > 0.f ? 1 : -1) : 0;
        int q1 = (fabsf(v.y) > thr) ? (v.y > 0.f ? 1 : -1) : 0;
        int q2 = (fabsf(v.z) > thr) ? (v.z > 0.f ? 1 : -1) : 0;
        int q3 = (fabsf(v.w) > thr) ? (v.w > 0.f ? 1 : -1) : 0;
        qw[i] = (q0 & 0xff) | ((q1 & 0xff) << 8) | ((q2 & 0xff) << 16) | ((q3 & 0xff) << 24);
    }
}

// ---- fused quant-A + int8 GEMM ----
// Block: 64 M-rows x full N=1024, 256 threads (4 waves). Wave w covers
// cols [w*256, w*256+256) in 4 chunks of 64; per chunk acc[4][4] (64 AGPR).
// Phase A: quantize x rows -> qa[64][1024] int8 in LDS, 16B-chunk XOR
// swizzle (chunk' = chunk ^ (row&7)) -> conflict-free writes AND reads.
// Phase B: NO barriers. af[4] ds_read_b128 per K-tile; bf[4] straight from
// qw (L2-resident) with static double-buffer (even/odd kt bodies).
// Epilogue per chunk: dequant * w_scale * i_scale + bias (ref op order).
__global__ __launch_bounds__(256, 2) void kfused(
    const float* __restrict__ x, const char* __restrict__ qw,
    const float* __restrict__ bias, const float* __restrict__ wscp,
    const float* __restrict__ maxp, float* __restrict__ out)
{
    __shared__ __align__(16) char qa[64 * 1024];
    __shared__ float sm[4];

    const int t = threadIdx.x;
    const int l = t & 63;
    const int w = t >> 6;          // 0..3
    const long m0 = (long)blockIdx.x * 64;

    // i_scale: redundant deterministic reduce of maxp[2048] (max = order-indep)
    float m = 0.f;
    #pragma unroll
    for (int j = 0; j < 8; ++j) m = fmaxf(m, maxp[t + 256 * j]);
    #pragma unroll
    for (int off = 1; off < 64; off <<= 1) m = fmaxf(m, __shfl_xor(m, off));
    if (l == 0) sm[w] = m;
    __syncthreads();
    const float isc = fmaxf(fmaxf(sm[0], sm[1]), fmaxf(sm[2], sm[3])) / 127.0f;
    const float rin = 1.0f / isc;  // one IEEE divide; per-elem mul below

    // Phase A: wave w quantizes rows w*16..w*16+15.
    // lane l, e=0..3: float4 #(e*64+l) of the row -> packed dword d=e*64+l.
    for (int j = 0; j < 16; ++j) {
        const int row = w * 16 + j;
        const float4* src = (const float4*)(x + (m0 + row) * MK_K);
        #pragma unroll
        for (int e = 0; e < 4; ++e) {
            float4 v = src[e * 64 + l];
            int i0 = (int)fminf(fmaxf(rintf(v.x * rin), -128.f), 127.f);
            int i1 = (int)fminf(fmaxf(rintf(v.y * rin), -128.f), 127.f);
            int i2 = (int)fminf(fmaxf(rintf(v.z * rin), -128.f), 127.f);
            int i3 = (int)fminf(fmaxf(rintf(v.w * rin), -128.f), 127.f);
            unsigned pk = (i0 & 0xff) | ((i1 & 0xff) << 8) | ((i2 & 0xff) << 16) | ((i3 & 0xff) << 24);
            const int d = e * 64 + l;                       // dword index in row
            const int dsw = ((((d >> 2) ^ (row & 7)) << 2) | (d & 3));
            *(unsigned*)(qa + row * 1024 + dsw * 4) = pk;
        }
    }
    __syncthreads();

    // Phase B: barrier-free GEMM. 4 n-chunks of 64 cols per wave.
    const float wsc = *wscp;
    const int crow = (l >> 4) * 4;
    const int ccol = l & 15;

    for (int nc = 0; nc < 4; ++nc) {
        const int nb = w * 256 + nc * 64;
        // bf base: col nb + i*16 + (l&15), k-slice (l>>4)*16 within K-tile
        const char* bq = qw + (long)(nb + (l & 15)) * MK_K + (l >> 4) * 16;

        int32x4 acc[4][4];
        #pragma unroll
        for (int mi = 0; mi < 4; ++mi)
            #pragma unroll
            for (int ni = 0; ni < 4; ++ni) acc[mi][ni] = (int32x4)0;

        int32x4 bfP[4], bfQ[4];
        #pragma unroll
        for (int i = 0; i < 4; ++i)
            bfP[i] = *(const int32x4*)(bq + i * 16 * MK_K);

        #pragma unroll 2
        for (int kp = 0; kp < 8; ++kp) {
            {   // even kt: consume bfP, prefetch kt+1 -> bfQ
                const int kt = 2 * kp;
                int32x4 af[4];
                #pragma unroll
                for (int i = 0; i < 4; ++i) {
                    int row = i * 16 + (l & 15);
                    int cc = (kt * 4 + (l >> 4)) ^ (row & 7);
                    af[i] = *(const int32x4*)(qa + row * 1024 + cc * 16);
                }
                #pragma unroll
                for (int i = 0; i < 4; ++i)
                    bfQ[i] = *(const int32x4*)(bq + i * 16 * MK_K + (kt + 1) * 64);
                #pragma unroll
                for (int mi = 0; mi < 4; ++mi)
                    #pragma unroll
                    for (int ni = 0; ni < 4; ++ni)
                        acc[mi][ni] = __builtin_amdgcn_mfma_i32_16x16x64_i8(
                            af[mi], bfP[ni], acc[mi][ni], 0, 0, 0);
            }
            {   // odd kt: consume bfQ, prefetch kt+2 -> bfP
                const int kt = 2 * kp + 1;
                int32x4 af[4];
                #pragma unroll
                for (int i = 0; i < 4; ++i) {
                    int row = i * 16 + (l & 15);
                    int cc = (kt * 4 + (l >> 4)) ^ (row & 7);
                    af[i] = *(const int32x4*)(qa + row * 1024 + cc * 16);
                }
                if (kt < 15) {
                    #pragma unroll
                    for (int i = 0; i < 4; ++i)
                        bfP[i] = *(const int32x4*)(bq + i * 16 * MK_K + (kt + 1) * 64);
                }
                #pragma unroll
                for (int mi = 0; mi < 4; ++mi)
                    #pragma unroll
                    for (int ni = 0; ni < 4; ++ni)
                        acc[mi][ni] = __builtin_amdgcn_mfma_i32_16x16x64_i8(
                            af[mi], bfQ[ni], acc[mi][ni], 0, 0, 0);
            }
        }

        // epilogue for this n-chunk: C/D layout col = lane&15, row = (lane>>4)*4 + reg
        const float s2 = wsc * 1.0f;  // keep op order: (acc*wsc)*isc + bias
        #pragma unroll
        for (int mi = 0; mi < 4; ++mi) {
            #pragma unroll
            for (int ni = 0; ni < 4; ++ni) {
                long r0 = m0 + mi * 16 + crow;
                int c = nb + ni * 16 + ccol;
                float b = bias[c];
                #pragma unroll
                for (int j = 0; j < 4; ++j) {
                    out[(r0 + j) * MK_N + c] = ((float)acc[mi][ni][j] * s2) * isc + b;
                }
            }
        }
    }
}

extern "C" void kernel_launch(void* const* d_in, const int* in_sizes, int n_in,
                              void* d_out, int out_size, void* d_ws, size_t ws_size,
                              hipStream_t stream) {
    const float* x = (const float*)d_in[0];
    const float* wt = (const float*)d_in[1];
    const float* bias = (const float*)d_in[2];
    float* out = (float*)d_out;

    if (ws_size < WS_NEEDED) return;

    char* ws = (char*)d_ws;
    float* wscp = (float*)(ws + 0);
    float* maxp = (float*)(ws + WS_MAXP_OFF);
    double* partials = (double*)(ws + WS_PART_OFF);
    char* qw = ws + WS_QW_OFF;

    const long n_x = (long)in_sizes[0];   // 33554432
    const long n4_x = n_x >> 2;

    kprep<<<2112, 256, 0, stream>>>((const float4*)x, (const float4*)wt, maxp, partials, n4_x);
    kquant_w<<<256, 256, 0, stream>>>((const float4*)wt, (unsigned*)qw, partials, wscp);
    kfused<<<MK_M / 64, 256, 0, stream>>>(x, qw, bias, wscp, maxp, out);
}